// Round 2
// baseline (286.039 us; speedup 1.0000x reference)
//
#include <hip/hip_runtime.h>

// STGraphConstructor: adj[b] = tanh(relu(A_b A_b^T) + I), A_b = [5096 x 64] fp32.
// R2 strategy:
//  - prep kernel: one-time fp32 -> (hi,lo) bf16 split into d_ws (5.2 MB, L2-resident)
//  - main kernel: MFMA fragments loaded DIRECTLY from global (L2 hit), no LDS/barrier
//  - swapped operand roles (D = Acol * Arow^T) so each lane holds 4 consecutive
//    COLUMNS of one row -> float4 nontemporal stores
//  - 3-product split-bf16 (hh + hl + lh) for fp32-grade accuracy at bf16 MFMA rate

#define NSP 5000
#define NTM 96
#define MM  5096
#define DD  64
#define BT  128
#define NTILE 40   // ceil(5096/128)

typedef __attribute__((ext_vector_type(8))) short short8;
typedef __attribute__((ext_vector_type(8))) unsigned short ushort8;
typedef __attribute__((ext_vector_type(4))) float f32x4;

__device__ __forceinline__ unsigned short bf16_rn(float x) {
  unsigned u = __float_as_uint(x);
  u += 0x7FFFu + ((u >> 16) & 1u);
  return (unsigned short)(u >> 16);
}
__device__ __forceinline__ float bf16_f32(unsigned short s) {
  return __uint_as_float(((unsigned)s) << 16);
}

// ---- prep: convert concat(sp,tm) [B][MM][DD] fp32 -> hi/lo bf16 panels ----
// grid covers B*MM*DD/8 threads; each thread converts 8 contiguous floats.
__global__ __launch_bounds__(256) void stg_prep_kernel(
    const float* __restrict__ sp, const float* __restrict__ tm,
    unsigned short* __restrict__ wsh, unsigned short* __restrict__ wsl) {
  const int tid = blockIdx.x * 256 + threadIdx.x;
  const int flat = tid * 8;                       // element index into [B][MM][DD]
  const int b = flat / (MM * DD);
  const int rem = flat - b * (MM * DD);
  const int m = rem / DD;
  const int d = rem - m * DD;
  const float* src = (m < NSP)
      ? sp + ((size_t)b * NSP + m) * DD + d
      : tm + ((size_t)b * NTM + (m - NSP)) * DD + d;
  const float4* s4 = reinterpret_cast<const float4*>(src);
  float f[8];
  {
    float4 v0 = s4[0], v1 = s4[1];
    f[0]=v0.x; f[1]=v0.y; f[2]=v0.z; f[3]=v0.w;
    f[4]=v1.x; f[5]=v1.y; f[6]=v1.z; f[7]=v1.w;
  }
  ushort8 H, L;
  #pragma unroll
  for (int i = 0; i < 8; ++i) {
    const unsigned short hi = bf16_rn(f[i]);
    H[i] = hi;
    L[i] = bf16_rn(f[i] - bf16_f32(hi));
  }
  *reinterpret_cast<ushort8*>(wsh + flat) = H;
  *reinterpret_cast<ushort8*>(wsl + flat) = L;
}

// ---- main: 128x128 tile per 256-thread block, fragments direct from global ----
__global__ __launch_bounds__(256) void stg_adj_kernel(
    const unsigned short* __restrict__ wsh,
    const unsigned short* __restrict__ wsl,
    float* __restrict__ out) {
  const int bi = blockIdx.x;   // output row tile
  const int bj = blockIdx.y;   // output col tile
  const int b  = blockIdx.z;
  const int t  = threadIdx.x;
  const int lane = t & 63;
  const int wave = t >> 6;
  const int wr = (wave >> 1) << 6;   // wave's 64x64 quadrant
  const int wc = (wave & 1) << 6;
  const int lr = lane & 15;
  const int lg = lane >> 4;

  const size_t pb = (size_t)b * MM * DD;
  const char* Xh = reinterpret_cast<const char*>(wsh + pb);
  const char* Xl = reinterpret_cast<const char*>(wsl + pb);
  const int gr0 = bi * BT + wr;
  const int gc0 = bj * BT + wc;

  // byte offsets of each fragment's 16B lane-read (clamped rows; OOB rows unused)
  unsigned offr[4], offc[4];
  #pragma unroll
  for (int m = 0; m < 4; ++m) {
    int rr = gr0 + m * 16 + lr; rr = rr < MM ? rr : MM - 1;
    offr[m] = (unsigned)rr * 128u + (unsigned)lg * 16u;
    int rc = gc0 + m * 16 + lr; rc = rc < MM ? rc : MM - 1;
    offc[m] = (unsigned)rc * 128u + (unsigned)lg * 16u;
  }

  f32x4 acc[4][4];
  #pragma unroll
  for (int m = 0; m < 4; ++m)
    #pragma unroll
    for (int n = 0; n < 4; ++n)
      acc[m][n] = (f32x4){0.f, 0.f, 0.f, 0.f};

  #pragma unroll
  for (int ks = 0; ks < 2; ++ks) {
    const unsigned ko = (unsigned)ks * 64u;
    short8 rh[4], rl[4], ch[4], cl[4];
    #pragma unroll
    for (int m = 0; m < 4; ++m) {
      rh[m] = *reinterpret_cast<const short8*>(Xh + offr[m] + ko);
      rl[m] = *reinterpret_cast<const short8*>(Xl + offr[m] + ko);
      ch[m] = *reinterpret_cast<const short8*>(Xh + offc[m] + ko);
      cl[m] = *reinterpret_cast<const short8*>(Xl + offc[m] + ko);
    }
    // D = Acol * Arow^T  => lane holds C[row = gr0+m*16+(l&15)][4 consecutive cols]
    #pragma unroll
    for (int m = 0; m < 4; ++m) {
      #pragma unroll
      for (int n = 0; n < 4; ++n) {
        acc[m][n] = __builtin_amdgcn_mfma_f32_16x16x32_bf16(ch[n], rh[m], acc[m][n], 0, 0, 0);
        acc[m][n] = __builtin_amdgcn_mfma_f32_16x16x32_bf16(ch[n], rl[m], acc[m][n], 0, 0, 0);
        acc[m][n] = __builtin_amdgcn_mfma_f32_16x16x32_bf16(cl[n], rh[m], acc[m][n], 0, 0, 0);
      }
    }
  }

  // ---- epilogue: tanh(relu(x) + eye), float4 nontemporal stores ----
  const size_t cbase = (size_t)b * MM * MM;
  int grs[4]; bool rv[4];
  #pragma unroll
  for (int m = 0; m < 4; ++m) { grs[m] = gr0 + m * 16 + lr; rv[m] = grs[m] < MM; }

  #pragma unroll
  for (int m = 0; m < 4; ++m) {
    float* rowp = out + cbase + (size_t)grs[m] * MM;
    #pragma unroll
    for (int n = 0; n < 4; ++n) {
      const int gc = gc0 + n * 16 + lg * 4;
      if (rv[m] && gc < MM) {     // gc multiple of 4, MM multiple of 4 => whole float4 valid
        f32x4 v;
        #pragma unroll
        for (int q = 0; q < 4; ++q) {
          float x = fmaxf(acc[m][n][q], 0.f);
          x += (grs[m] == gc + q) ? 1.f : 0.f;
          // tanh(x), x>=0: 1 - 2/(exp(2x)+1); exp2-based, saturates to 1.
          const float e = __builtin_amdgcn_exp2f(x * 2.8853900817779268f);
          v[q] = 1.f - 2.f * __builtin_amdgcn_rcpf(e + 1.f);
        }
        __builtin_nontemporal_store(v, reinterpret_cast<f32x4*>(rowp + gc));
      }
    }
  }
}

extern "C" void kernel_launch(void* const* d_in, const int* in_sizes, int n_in,
                              void* d_out, int out_size, void* d_ws, size_t ws_size,
                              hipStream_t stream) {
  const float* sp = (const float*)d_in[0];
  const float* tm = (const float*)d_in[1];
  float* out = (float*)d_out;
  const int B = in_sizes[0] / (NSP * DD);   // = 4
  unsigned short* wsh = (unsigned short*)d_ws;
  unsigned short* wsl = wsh + (size_t)B * MM * DD;

  const int prep_threads = B * MM * DD / 8;           // 163072
  stg_prep_kernel<<<dim3(prep_threads / 256), dim3(256), 0, stream>>>(sp, tm, wsh, wsl);

  dim3 grid(NTILE, NTILE, B);
  stg_adj_kernel<<<grid, dim3(256), 0, stream>>>(wsh, wsl, out);
}

// Round 3
// 140.870 us; speedup vs baseline: 2.0305x; 2.0305x over previous
//
#include <hip/hip_runtime.h>

// STGraphConstructor: adj[b] = tanh(relu(A_b A_b^T) + I), A_b = [5096 x 64] fp32.
// R3:
//  - prep kernel: one-time fp32 -> (hi,lo) bf16 split into d_ws (validated R2: FETCH=20MB)
//  - main kernel: fragments direct from global (L2-hit), swapped operands
//    (D = Acol*Arow^T: lane holds row=l&15, 4 consecutive cols)
//  - epilogue: per-wave LDS transpose (padded stride 68 floats, bank-uniform)
//    -> PLAIN float4 stores, 4 rows x 256B contiguous per instruction
//    (R2 lesson: nontemporal scattered stores => 1.54x write amplification)

#define NSP 5000
#define NTM 96
#define MM  5096
#define DD  64
#define BT  128
#define NTILE 40   // ceil(5096/128)
#define LROW 68    // padded floats per epilogue-LDS row (17 x 16B granules)

typedef __attribute__((ext_vector_type(8))) short short8;
typedef __attribute__((ext_vector_type(8))) unsigned short ushort8;
typedef __attribute__((ext_vector_type(4))) float f32x4;

__device__ __forceinline__ unsigned short bf16_rn(float x) {
  unsigned u = __float_as_uint(x);
  u += 0x7FFFu + ((u >> 16) & 1u);
  return (unsigned short)(u >> 16);
}
__device__ __forceinline__ float bf16_f32(unsigned short s) {
  return __uint_as_float(((unsigned)s) << 16);
}

// ---- prep: convert concat(sp,tm) [B][MM][DD] fp32 -> hi/lo bf16 panels ----
__global__ __launch_bounds__(256) void stg_prep_kernel(
    const float* __restrict__ sp, const float* __restrict__ tm,
    unsigned short* __restrict__ wsh, unsigned short* __restrict__ wsl) {
  const int tid = blockIdx.x * 256 + threadIdx.x;
  const int flat = tid * 8;
  const int b = flat / (MM * DD);
  const int rem = flat - b * (MM * DD);
  const int m = rem / DD;
  const int d = rem - m * DD;
  const float* src = (m < NSP)
      ? sp + ((size_t)b * NSP + m) * DD + d
      : tm + ((size_t)b * NTM + (m - NSP)) * DD + d;
  const float4* s4 = reinterpret_cast<const float4*>(src);
  float f[8];
  {
    float4 v0 = s4[0], v1 = s4[1];
    f[0]=v0.x; f[1]=v0.y; f[2]=v0.z; f[3]=v0.w;
    f[4]=v1.x; f[5]=v1.y; f[6]=v1.z; f[7]=v1.w;
  }
  ushort8 H, L;
  #pragma unroll
  for (int i = 0; i < 8; ++i) {
    const unsigned short hi = bf16_rn(f[i]);
    H[i] = hi;
    L[i] = bf16_rn(f[i] - bf16_f32(hi));
  }
  *reinterpret_cast<ushort8*>(wsh + flat) = H;
  *reinterpret_cast<ushort8*>(wsl + flat) = L;
}

// ---- main: 128x128 tile per 256-thread block ----
__global__ __launch_bounds__(256) void stg_adj_kernel(
    const unsigned short* __restrict__ wsh,
    const unsigned short* __restrict__ wsl,
    float* __restrict__ out) {
  __shared__ float elds[4][16 * LROW];   // 4.25 KB per wave
  const int bi = blockIdx.x;
  const int bj = blockIdx.y;
  const int b  = blockIdx.z;
  const int t  = threadIdx.x;
  const int lane = t & 63;
  const int wave = t >> 6;
  const int wr = (wave >> 1) << 6;   // wave's 64x64 quadrant
  const int wc = (wave & 1) << 6;
  const int lr = lane & 15;
  const int lg = lane >> 4;

  const size_t pb = (size_t)b * MM * DD;
  const char* Xh = reinterpret_cast<const char*>(wsh + pb);
  const char* Xl = reinterpret_cast<const char*>(wsl + pb);
  const int gr0 = bi * BT + wr;
  const int gc0 = bj * BT + wc;

  unsigned offr[4], offc[4];
  #pragma unroll
  for (int m = 0; m < 4; ++m) {
    int rr = gr0 + m * 16 + lr; rr = rr < MM ? rr : MM - 1;
    offr[m] = (unsigned)rr * 128u + (unsigned)lg * 16u;
    int rc = gc0 + m * 16 + lr; rc = rc < MM ? rc : MM - 1;
    offc[m] = (unsigned)rc * 128u + (unsigned)lg * 16u;
  }

  f32x4 acc[4][4];
  #pragma unroll
  for (int m = 0; m < 4; ++m)
    #pragma unroll
    for (int n = 0; n < 4; ++n)
      acc[m][n] = (f32x4){0.f, 0.f, 0.f, 0.f};

  #pragma unroll
  for (int ks = 0; ks < 2; ++ks) {
    const unsigned ko = (unsigned)ks * 64u;
    short8 rh[4], rl4[4], ch[4], cl4[4];
    #pragma unroll
    for (int m = 0; m < 4; ++m) {
      rh[m]  = *reinterpret_cast<const short8*>(Xh + offr[m] + ko);
      rl4[m] = *reinterpret_cast<const short8*>(Xl + offr[m] + ko);
      ch[m]  = *reinterpret_cast<const short8*>(Xh + offc[m] + ko);
      cl4[m] = *reinterpret_cast<const short8*>(Xl + offc[m] + ko);
    }
    #pragma unroll
    for (int m = 0; m < 4; ++m) {
      #pragma unroll
      for (int n = 0; n < 4; ++n) {
        acc[m][n] = __builtin_amdgcn_mfma_f32_16x16x32_bf16(ch[n], rh[m],  acc[m][n], 0, 0, 0);
        acc[m][n] = __builtin_amdgcn_mfma_f32_16x16x32_bf16(ch[n], rl4[m], acc[m][n], 0, 0, 0);
        acc[m][n] = __builtin_amdgcn_mfma_f32_16x16x32_bf16(cl4[n], rh[m], acc[m][n], 0, 0, 0);
      }
    }
  }

  // ---- epilogue: act -> per-wave LDS transpose -> coalesced 256B-segment stores
  const size_t cbase = (size_t)b * MM * MM;
  const int myrow = gr0 + lr;          // + m*16
  #pragma unroll
  for (int m = 0; m < 4; ++m) {
    const int grm = myrow + m * 16;
    __syncthreads();                   // protect elds from previous iteration's readers
    #pragma unroll
    for (int n = 0; n < 4; ++n) {
      f32x4 v;
      #pragma unroll
      for (int q = 0; q < 4; ++q) {
        float x = fmaxf(acc[m][n][q], 0.f);
        const int gc = gc0 + n * 16 + lg * 4 + q;
        x += (grm == gc) ? 1.f : 0.f;
        const float e = __builtin_amdgcn_exp2f(x * 2.8853900817779268f);
        v[q] = 1.f - 2.f * __builtin_amdgcn_rcpf(e + 1.f);
      }
      *reinterpret_cast<f32x4*>(&elds[wave][lr * LROW + n * 16 + lg * 4]) = v;
    }
    __syncthreads();                   // writes visible to whole wave (and block)
    #pragma unroll
    for (int p = 0; p < 4; ++p) {
      const int rloc = p * 4 + lg;                 // local row 0..15
      const int gr = gr0 + m * 16 + rloc;
      const int gc = gc0 + lr * 4;
      if (gr < MM && gc < MM) {
        const f32x4 v = *reinterpret_cast<const f32x4*>(&elds[wave][rloc * LROW + lr * 4]);
        *reinterpret_cast<f32x4*>(out + cbase + (size_t)gr * MM + gc) = v;
      }
    }
  }
}

extern "C" void kernel_launch(void* const* d_in, const int* in_sizes, int n_in,
                              void* d_out, int out_size, void* d_ws, size_t ws_size,
                              hipStream_t stream) {
  const float* sp = (const float*)d_in[0];
  const float* tm = (const float*)d_in[1];
  float* out = (float*)d_out;
  const int B = in_sizes[0] / (NSP * DD);   // = 4
  unsigned short* wsh = (unsigned short*)d_ws;
  unsigned short* wsl = wsh + (size_t)B * MM * DD;

  const int prep_threads = B * MM * DD / 8;
  stg_prep_kernel<<<dim3(prep_threads / 256), dim3(256), 0, stream>>>(sp, tm, wsh, wsl);

  dim3 grid(NTILE, NTILE, B);
  stg_adj_kernel<<<grid, dim3(256), 0, stream>>>(wsh, wsl, out);
}

// Round 4
// 140.734 us; speedup vs baseline: 2.0325x; 1.0010x over previous
//
#include <hip/hip_runtime.h>

// STGraphConstructor: adj[b] = tanh(relu(A_b A_b^T) + I), A_b = [5096 x 64] fp32.
// R4:
//  - prep kernel: one-time fp32 -> (hi,lo) bf16 split into d_ws (validated: FETCH ~20MB)
//  - main kernel: fragments direct from L2, swapped operands (lane=row, 4 consecutive
//    cols), NO LDS, NO barriers, plain float4 stores (L2 write-combining assembles
//    full lines; R2 lesson: only nontemporal breaks this)
//  - XCD batch-pinning: 1D grid, batch b -> XCD pair {2b,2b+1} so each XCD's 4MB L2
//    holds exactly one batch's 1.3MB panels (kills L3 round-trips on fragment loads)

#define NSP 5000
#define NTM 96
#define MM  5096
#define DD  64
#define BT  128
#define NTILE 40   // ceil(5096/128)

typedef __attribute__((ext_vector_type(8))) short short8;
typedef __attribute__((ext_vector_type(8))) unsigned short ushort8;
typedef __attribute__((ext_vector_type(4))) float f32x4;

__device__ __forceinline__ unsigned short bf16_rn(float x) {
  unsigned u = __float_as_uint(x);
  u += 0x7FFFu + ((u >> 16) & 1u);
  return (unsigned short)(u >> 16);
}
__device__ __forceinline__ float bf16_f32(unsigned short s) {
  return __uint_as_float(((unsigned)s) << 16);
}

// ---- prep: convert concat(sp,tm) [B][MM][DD] fp32 -> hi/lo bf16 panels ----
__global__ __launch_bounds__(256) void stg_prep_kernel(
    const float* __restrict__ sp, const float* __restrict__ tm,
    unsigned short* __restrict__ wsh, unsigned short* __restrict__ wsl) {
  const int tid = blockIdx.x * 256 + threadIdx.x;
  const int flat = tid * 8;
  const int b = flat / (MM * DD);
  const int rem = flat - b * (MM * DD);
  const int m = rem / DD;
  const int d = rem - m * DD;
  const float* src = (m < NSP)
      ? sp + ((size_t)b * NSP + m) * DD + d
      : tm + ((size_t)b * NTM + (m - NSP)) * DD + d;
  const float4* s4 = reinterpret_cast<const float4*>(src);
  float f[8];
  {
    float4 v0 = s4[0], v1 = s4[1];
    f[0]=v0.x; f[1]=v0.y; f[2]=v0.z; f[3]=v0.w;
    f[4]=v1.x; f[5]=v1.y; f[6]=v1.z; f[7]=v1.w;
  }
  ushort8 H, L;
  #pragma unroll
  for (int i = 0; i < 8; ++i) {
    const unsigned short hi = bf16_rn(f[i]);
    H[i] = hi;
    L[i] = bf16_rn(f[i] - bf16_f32(hi));
  }
  *reinterpret_cast<ushort8*>(wsh + flat) = H;
  *reinterpret_cast<ushort8*>(wsl + flat) = L;
}

// ---- main: 128x128 tile per 256-thread block, no LDS, no barriers ----
__global__ __launch_bounds__(256) void stg_adj_kernel(
    const unsigned short* __restrict__ wsh,
    const unsigned short* __restrict__ wsl,
    float* __restrict__ out) {
  // XCD batch-pinning decode: wid%8 selects XCD; batch b owns residues {2b,2b+1}
  const int wid = blockIdx.x;
  const int u = wid >> 3;          // 0..799
  const int x = wid & 7;
  const int b = x >> 1;            // batch 0..3
  const int tt = u * 2 + (x & 1);  // tile 0..1599
  const int bi = tt / NTILE;
  const int bj = tt - bi * NTILE;

  const int t  = threadIdx.x;
  const int lane = t & 63;
  const int wave = t >> 6;
  const int wr = (wave >> 1) << 6;   // wave's 64x64 quadrant
  const int wc = (wave & 1) << 6;
  const int lr = lane & 15;
  const int lg = lane >> 4;

  const size_t pb = (size_t)b * MM * DD;
  const char* Xh = reinterpret_cast<const char*>(wsh + pb);
  const char* Xl = reinterpret_cast<const char*>(wsl + pb);
  const int gr0 = bi * BT + wr;
  const int gc0 = bj * BT + wc;

  unsigned offr[4], offc[4];
  #pragma unroll
  for (int m = 0; m < 4; ++m) {
    int rr = gr0 + m * 16 + lr; rr = rr < MM ? rr : MM - 1;
    offr[m] = (unsigned)rr * 128u + (unsigned)lg * 16u;
    int rc = gc0 + m * 16 + lr; rc = rc < MM ? rc : MM - 1;
    offc[m] = (unsigned)rc * 128u + (unsigned)lg * 16u;
  }

  f32x4 acc[4][4];
  #pragma unroll
  for (int m = 0; m < 4; ++m)
    #pragma unroll
    for (int n = 0; n < 4; ++n)
      acc[m][n] = (f32x4){0.f, 0.f, 0.f, 0.f};

  #pragma unroll
  for (int ks = 0; ks < 2; ++ks) {
    const unsigned ko = (unsigned)ks * 64u;
    short8 rh[4], rl4[4], ch[4], cl4[4];
    #pragma unroll
    for (int m = 0; m < 4; ++m) {
      rh[m]  = *reinterpret_cast<const short8*>(Xh + offr[m] + ko);
      rl4[m] = *reinterpret_cast<const short8*>(Xl + offr[m] + ko);
      ch[m]  = *reinterpret_cast<const short8*>(Xh + offc[m] + ko);
      cl4[m] = *reinterpret_cast<const short8*>(Xl + offc[m] + ko);
    }
    // D = Acol * Arow^T => lane holds C[row = gr0+m*16+(l&15)][4 consecutive cols]
    #pragma unroll
    for (int m = 0; m < 4; ++m) {
      #pragma unroll
      for (int n = 0; n < 4; ++n) {
        acc[m][n] = __builtin_amdgcn_mfma_f32_16x16x32_bf16(ch[n], rh[m],  acc[m][n], 0, 0, 0);
        acc[m][n] = __builtin_amdgcn_mfma_f32_16x16x32_bf16(ch[n], rl4[m], acc[m][n], 0, 0, 0);
        acc[m][n] = __builtin_amdgcn_mfma_f32_16x16x32_bf16(cl4[n], rh[m], acc[m][n], 0, 0, 0);
      }
    }
  }

  // ---- epilogue: tanh(relu(x)+eye), direct plain float4 stores ----
  const size_t cbase = (size_t)b * MM * MM;
  #pragma unroll
  for (int m = 0; m < 4; ++m) {
    const int gr = gr0 + m * 16 + lr;
    if (gr < MM) {
      float* rowp = out + cbase + (size_t)gr * MM;
      #pragma unroll
      for (int n = 0; n < 4; ++n) {
        const int gc = gc0 + n * 16 + lg * 4;
        if (gc < MM) {   // gc multiple of 4, MM multiple of 4 => whole float4 valid
          f32x4 v;
          #pragma unroll
          for (int q = 0; q < 4; ++q) {
            float xv = fmaxf(acc[m][n][q], 0.f);
            xv += (gr == gc + q) ? 1.f : 0.f;
            const float e = __builtin_amdgcn_exp2f(xv * 2.8853900817779268f);
            v[q] = 1.f - 2.f * __builtin_amdgcn_rcpf(e + 1.f);
          }
          *reinterpret_cast<f32x4*>(rowp + gc) = v;
        }
      }
    }
  }
}

extern "C" void kernel_launch(void* const* d_in, const int* in_sizes, int n_in,
                              void* d_out, int out_size, void* d_ws, size_t ws_size,
                              hipStream_t stream) {
  const float* sp = (const float*)d_in[0];
  const float* tm = (const float*)d_in[1];
  float* out = (float*)d_out;
  const int B = in_sizes[0] / (NSP * DD);   // = 4
  unsigned short* wsh = (unsigned short*)d_ws;
  unsigned short* wsl = wsh + (size_t)B * MM * DD;

  const int prep_threads = B * MM * DD / 8;
  stg_prep_kernel<<<dim3(prep_threads / 256), dim3(256), 0, stream>>>(sp, tm, wsh, wsl);

  stg_adj_kernel<<<dim3(B * NTILE * NTILE), dim3(256), 0, stream>>>(wsh, wsl, out);
}